// Round 8
// baseline (77.241 us; speedup 1.0000x reference)
//
#include <hip/hip_runtime.h>

// Local windowed 2D autocorrelation.
// x: [8, 64, 128, 128] fp32; out: [8, 64, 31, 31, 8, 8] fp32.
// KH=KW=8, SH=SW=4, no padding.
//
// Round 8 = round 7 + PERSISTENT BLOCKS (grid-stride over tiles).
// Evidence: round 6/7 ran 8192 short-lived (~1.5us) blocks and profiled at
// 21.6% occupancy with VALUBusy 43% / HBM 24% -- nothing saturated, i.e.
// residency-starved: blocks retire faster than the CP refills the CUs.
// Grid = 1536 = 6 blocks/CU, all co-resident (30/32 waves, 95KB/160KB LDS);
// each block loops over ~5-6 tiles. Inner code identical to round 7.
//
// Structure:
//  - block = 320 threads = 5 waves; wave k in 0..4 computes output row oy=k
//    for 62 windows (31 w-positions x 2 window-rows); rows 5..7 from the
//    autocorr symmetry corr(dy,dx)=corr(-dy,-dx) (reversal + 1 edge value).
//  - results assembled in LDS (15.9 KB/block), streamed out as contiguous
//    full-line float4 runs by the whole block (round 5 lesson: scattered
//    32 B per-wave stores caused 3.75x HBM write amplification).
//  - LDS float4 slot index XOR-swizzled by (w&7): conflict-free on both the
//    scattered compute-phase writes and the linear copy-out reads.
//  - second __syncthreads after copy-out: next iteration's LDS writes must
//    not race this iteration's copy-out reads (correctness must not depend
//    on timing).

#define NH 31
#define NW 31
#define NTILES (512 * 16)
#define GRID 1536

typedef float f32x4 __attribute__((ext_vector_type(4)));

__device__ __forceinline__ void loadrow(const float* p, float r[8]) {
  f32x4 a = *reinterpret_cast<const f32x4*>(p);
  f32x4 b = *reinterpret_cast<const f32x4*>(p + 4);
  r[0] = a.x; r[1] = a.y; r[2] = a.z; r[3] = a.w;
  r[4] = b.x; r[5] = b.y; r[6] = b.z; r[7] = b.w;
}

// Task for dy = -D (output row oy = 4-D), D in 1..4.
// acc[ox] = sum_{i=D..7} sum_j W[i][j] * W[i-D][j+ox-4]
// e (if WE) = sum_{i=D..7} sum_{j=4..7} W[i-D][j] * W[i][j-4]   (mirror edge)
template <int D, bool WE>
__device__ __forceinline__ void corr_task(const float* src, float acc[8], float& e) {
  float R[D + 1][8];
#pragma unroll
  for (int i = 0; i < 8; ++i) {
    const int ca = i % (D + 1);
    loadrow(src + i * 128, R[ca]);
    if (i >= D) {
      const int cb = (i - D) % (D + 1);
#pragma unroll
      for (int ox = 0; ox < 8; ++ox) {
#pragma unroll
        for (int j = 0; j < 8; ++j) {
          const int jj = j + ox - 4;
          if (jj < 0 || jj > 7) continue;  // compile-time after unroll
          acc[ox] += R[ca][j] * R[cb][jj];
        }
      }
      if (WE) {
#pragma unroll
        for (int j = 4; j < 8; ++j) e += R[cb][j] * R[ca][j - 4];
      }
    }
  }
}

// dy = 0 task: acc[ox] for ox=0..4 (row 4 is self-mirrored).
__device__ __forceinline__ void corr_task0(const float* src, float acc[5]) {
  float r[8];
#pragma unroll
  for (int i = 0; i < 8; ++i) {
    loadrow(src + i * 128, r);
#pragma unroll
    for (int ox = 0; ox < 5; ++ox) {
#pragma unroll
      for (int j = 0; j < 8; ++j) {
        const int jj = j + ox - 4;
        if (jj < 0 || jj > 7) continue;
        acc[ox] += r[j] * r[jj];
      }
    }
  }
}

__global__ __launch_bounds__(320) void lacorr2d_kernel(
    const float* __restrict__ x, float* __restrict__ out) {
  __shared__ __align__(16) float lds[2][31][64];

  const int wave = threadIdx.x >> 6;   // 0..4 : oy task
  const int lane = threadIdx.x & 63;
  const int w    = lane & 31;          // window col (31 = dead lane)
  const int hh   = lane >> 5;          // 0/1 within window-row pair
  const int sw   = (w < NW ? w : 0) & 7;

  for (int tile = blockIdx.x; tile < NTILES; tile += GRID) {
    const int hp = tile & 15;          // window-row pair
    const int bc = tile >> 4;          // 0..511
    const int h  = hp * 2 + hh;        // 0..31 (31 invalid)
    const bool valid = (w < NW) && (h < NH);
    const int hc = valid ? h : 0;
    const int wc = valid ? w : 0;

    const float* src = x + (size_t)bc * (128 * 128) + (size_t)(hc * 4) * 128 + wc * 4;
    float* wbase = &lds[hh][wc][0];

    float acc[8] = {0.f, 0.f, 0.f, 0.f, 0.f, 0.f, 0.f, 0.f};
    float e = 0.f;

#define LDS_ST(e4, a, b, c, d)                                              \
  do {                                                                      \
    f32x4 v_ = {a, b, c, d};                                                \
    *reinterpret_cast<f32x4*>(wbase + (((e4) ^ sw) << 2)) = v_;             \
  } while (0)

    if (wave == 0) {                   // oy=0, dy=-4 (unpaired row)
      corr_task<4, false>(src, acc, e);
      if (valid) {
        LDS_ST(0, acc[0], acc[1], acc[2], acc[3]);
        LDS_ST(1, acc[4], acc[5], acc[6], acc[7]);
      }
    } else if (wave == 1) {            // oy=1 & mirror oy=7
      corr_task<3, true>(src, acc, e);
      if (valid) {
        LDS_ST(2,  acc[0], acc[1], acc[2], acc[3]);
        LDS_ST(3,  acc[4], acc[5], acc[6], acc[7]);
        LDS_ST(14, e,      acc[7], acc[6], acc[5]);
        LDS_ST(15, acc[4], acc[3], acc[2], acc[1]);
      }
    } else if (wave == 2) {            // oy=2 & mirror oy=6
      corr_task<2, true>(src, acc, e);
      if (valid) {
        LDS_ST(4,  acc[0], acc[1], acc[2], acc[3]);
        LDS_ST(5,  acc[4], acc[5], acc[6], acc[7]);
        LDS_ST(12, e,      acc[7], acc[6], acc[5]);
        LDS_ST(13, acc[4], acc[3], acc[2], acc[1]);
      }
    } else if (wave == 3) {            // oy=3 & mirror oy=5
      corr_task<1, true>(src, acc, e);
      if (valid) {
        LDS_ST(6,  acc[0], acc[1], acc[2], acc[3]);
        LDS_ST(7,  acc[4], acc[5], acc[6], acc[7]);
        LDS_ST(10, e,      acc[7], acc[6], acc[5]);
        LDS_ST(11, acc[4], acc[3], acc[2], acc[1]);
      }
    } else {                           // oy=4, dy=0 (self-mirrored row)
      float a5[5] = {0.f, 0.f, 0.f, 0.f, 0.f};
      corr_task0(src, a5);
      if (valid) {
        LDS_ST(8, a5[0], a5[1], a5[2], a5[3]);
        LDS_ST(9, a5[4], a5[3], a5[2], a5[1]);
      }
    }
#undef LDS_ST

    __syncthreads();

    // Stream the assembled tile to global: two contiguous 7936 B runs
    // (31 windows x 256 B each), full cache lines, lane-consecutive float4s.
#pragma unroll
    for (int h2 = 0; h2 < 2; ++h2) {
      const int hrow = hp * 2 + h2;
      if (hrow >= NH) continue;  // block-uniform
      float* orun = out + (size_t)(bc * NH + hrow) * NW * 64;
      for (int idx = threadIdx.x; idx < NW * 16; idx += 320) {
        const int ww = idx >> 4;
        const int e4 = idx & 15;
        f32x4 v = *reinterpret_cast<const f32x4*>(&lds[h2][ww][(e4 ^ (ww & 7)) << 2]);
        *reinterpret_cast<f32x4*>(orun + idx * 4) = v;
      }
    }

    __syncthreads();  // protect LDS from next iteration's compute writes
  }
}

extern "C" void kernel_launch(void* const* d_in, const int* in_sizes, int n_in,
                              void* d_out, int out_size, void* d_ws, size_t ws_size,
                              hipStream_t stream) {
  const float* x = (const float*)d_in[0];
  float* out = (float*)d_out;
  lacorr2d_kernel<<<GRID, 320, 0, stream>>>(x, out);
}

// Round 9
// 77.216 us; speedup vs baseline: 1.0003x; 1.0003x over previous
//
#include <hip/hip_runtime.h>

// Local windowed 2D autocorrelation.
// x: [8, 64, 128, 128] fp32; out: [8, 64, 31, 31, 8, 8] fp32.
// KH=KW=8, SH=SW=4, no padding.
//
// Round 9 = round 8 with the grid sized to RESIDENCY, not beyond it.
// Round 8 lesson: VGPR=92 (grid-stride loop state) -> 5 waves/SIMD -> only
// 4 blocks/CU resident; grid=1536 oversubscribed 1.5x -> 512 blocks ran
// serially after the rest, hence the regression + 13.8% avg occupancy.
// Grid = 1024 = 4 blocks/CU, all co-resident from t=0; 8192 tiles / 1024 =
// exactly 8 tiles per block (no tail). Tiles consecutive per block: same bc
// plane, adjacent hp -> 4 input rows shared between successive tiles (L1).
//
// Structure (unchanged):
//  - block = 320 threads = 5 waves; wave k in 0..4 computes output row oy=k
//    for 62 windows (31 w-positions x 2 window-rows); rows 5..7 from the
//    autocorr symmetry corr(dy,dx)=corr(-dy,-dx) (reversal + 1 edge value).
//  - results assembled in LDS (15.9 KB/block), streamed out as contiguous
//    full-line float4 runs (round 5: scattered 32 B stores = 3.75x write amp).
//  - LDS float4 slot XOR-swizzled by (w&7): conflict-free writes and reads.
//  - syncthreads after copy-out protects LDS reuse across tile iterations.

#define NH 31
#define NW 31
#define GRID 1024
#define TILES_PER_BLOCK 8

typedef float f32x4 __attribute__((ext_vector_type(4)));

__device__ __forceinline__ void loadrow(const float* p, float r[8]) {
  f32x4 a = *reinterpret_cast<const f32x4*>(p);
  f32x4 b = *reinterpret_cast<const f32x4*>(p + 4);
  r[0] = a.x; r[1] = a.y; r[2] = a.z; r[3] = a.w;
  r[4] = b.x; r[5] = b.y; r[6] = b.z; r[7] = b.w;
}

// Task for dy = -D (output row oy = 4-D), D in 1..4.
// acc[ox] = sum_{i=D..7} sum_j W[i][j] * W[i-D][j+ox-4]
// e (if WE) = sum_{i=D..7} sum_{j=4..7} W[i-D][j] * W[i][j-4]   (mirror edge)
template <int D, bool WE>
__device__ __forceinline__ void corr_task(const float* src, float acc[8], float& e) {
  float R[D + 1][8];
#pragma unroll
  for (int i = 0; i < 8; ++i) {
    const int ca = i % (D + 1);
    loadrow(src + i * 128, R[ca]);
    if (i >= D) {
      const int cb = (i - D) % (D + 1);
#pragma unroll
      for (int ox = 0; ox < 8; ++ox) {
#pragma unroll
        for (int j = 0; j < 8; ++j) {
          const int jj = j + ox - 4;
          if (jj < 0 || jj > 7) continue;  // compile-time after unroll
          acc[ox] += R[ca][j] * R[cb][jj];
        }
      }
      if (WE) {
#pragma unroll
        for (int j = 4; j < 8; ++j) e += R[cb][j] * R[ca][j - 4];
      }
    }
  }
}

// dy = 0 task: acc[ox] for ox=0..4 (row 4 is self-mirrored).
__device__ __forceinline__ void corr_task0(const float* src, float acc[5]) {
  float r[8];
#pragma unroll
  for (int i = 0; i < 8; ++i) {
    loadrow(src + i * 128, r);
#pragma unroll
    for (int ox = 0; ox < 5; ++ox) {
#pragma unroll
      for (int j = 0; j < 8; ++j) {
        const int jj = j + ox - 4;
        if (jj < 0 || jj > 7) continue;
        acc[ox] += r[j] * r[jj];
      }
    }
  }
}

__global__ __launch_bounds__(320) void lacorr2d_kernel(
    const float* __restrict__ x, float* __restrict__ out) {
  __shared__ __align__(16) float lds[2][31][64];

  const int wave = threadIdx.x >> 6;   // 0..4 : oy task
  const int lane = threadIdx.x & 63;
  const int w    = lane & 31;          // window col (31 = dead lane)
  const int hh   = lane >> 5;          // 0/1 within window-row pair
  const int sw   = (w < NW ? w : 0) & 7;

  const int tile0 = blockIdx.x * TILES_PER_BLOCK;

  for (int it = 0; it < TILES_PER_BLOCK; ++it) {
    const int tile = tile0 + it;
    const int hp = tile & 15;          // window-row pair
    const int bc = tile >> 4;          // 0..511
    const int h  = hp * 2 + hh;        // 0..31 (31 invalid)
    const bool valid = (w < NW) && (h < NH);
    const int hc = valid ? h : 0;
    const int wc = valid ? w : 0;

    const float* src = x + (size_t)bc * (128 * 128) + (size_t)(hc * 4) * 128 + wc * 4;
    float* wbase = &lds[hh][wc][0];

    float acc[8] = {0.f, 0.f, 0.f, 0.f, 0.f, 0.f, 0.f, 0.f};
    float e = 0.f;

#define LDS_ST(e4, a, b, c, d)                                              \
  do {                                                                      \
    f32x4 v_ = {a, b, c, d};                                                \
    *reinterpret_cast<f32x4*>(wbase + (((e4) ^ sw) << 2)) = v_;             \
  } while (0)

    if (wave == 0) {                   // oy=0, dy=-4 (unpaired row)
      corr_task<4, false>(src, acc, e);
      if (valid) {
        LDS_ST(0, acc[0], acc[1], acc[2], acc[3]);
        LDS_ST(1, acc[4], acc[5], acc[6], acc[7]);
      }
    } else if (wave == 1) {            // oy=1 & mirror oy=7
      corr_task<3, true>(src, acc, e);
      if (valid) {
        LDS_ST(2,  acc[0], acc[1], acc[2], acc[3]);
        LDS_ST(3,  acc[4], acc[5], acc[6], acc[7]);
        LDS_ST(14, e,      acc[7], acc[6], acc[5]);
        LDS_ST(15, acc[4], acc[3], acc[2], acc[1]);
      }
    } else if (wave == 2) {            // oy=2 & mirror oy=6
      corr_task<2, true>(src, acc, e);
      if (valid) {
        LDS_ST(4,  acc[0], acc[1], acc[2], acc[3]);
        LDS_ST(5,  acc[4], acc[5], acc[6], acc[7]);
        LDS_ST(12, e,      acc[7], acc[6], acc[5]);
        LDS_ST(13, acc[4], acc[3], acc[2], acc[1]);
      }
    } else if (wave == 3) {            // oy=3 & mirror oy=5
      corr_task<1, true>(src, acc, e);
      if (valid) {
        LDS_ST(6,  acc[0], acc[1], acc[2], acc[3]);
        LDS_ST(7,  acc[4], acc[5], acc[6], acc[7]);
        LDS_ST(10, e,      acc[7], acc[6], acc[5]);
        LDS_ST(11, acc[4], acc[3], acc[2], acc[1]);
      }
    } else {                           // oy=4, dy=0 (self-mirrored row)
      float a5[5] = {0.f, 0.f, 0.f, 0.f, 0.f};
      corr_task0(src, a5);
      if (valid) {
        LDS_ST(8, a5[0], a5[1], a5[2], a5[3]);
        LDS_ST(9, a5[4], a5[3], a5[2], a5[1]);
      }
    }
#undef LDS_ST

    __syncthreads();

    // Stream the assembled tile to global: two contiguous 7936 B runs
    // (31 windows x 256 B each), full cache lines, lane-consecutive float4s.
#pragma unroll
    for (int h2 = 0; h2 < 2; ++h2) {
      const int hrow = hp * 2 + h2;
      if (hrow >= NH) continue;  // block-uniform
      float* orun = out + (size_t)(bc * NH + hrow) * NW * 64;
      for (int idx = threadIdx.x; idx < NW * 16; idx += 320) {
        const int ww = idx >> 4;
        const int e4 = idx & 15;
        f32x4 v = *reinterpret_cast<const f32x4*>(&lds[h2][ww][(e4 ^ (ww & 7)) << 2]);
        *reinterpret_cast<f32x4*>(orun + idx * 4) = v;
      }
    }

    __syncthreads();  // protect LDS from next iteration's compute writes
  }
}

extern "C" void kernel_launch(void* const* d_in, const int* in_sizes, int n_in,
                              void* d_out, int out_size, void* d_ws, size_t ws_size,
                              hipStream_t stream) {
  const float* x = (const float*)d_in[0];
  float* out = (float*)d_out;
  lacorr2d_kernel<<<GRID, 320, 0, stream>>>(x, out);
}

// Round 10
// 42.016 us; speedup vs baseline: 1.8384x; 1.8378x over previous
//
#include <hip/hip_runtime.h>

// Local windowed 2D autocorrelation.
// x: [8, 64, 128, 128] fp32; out: [8, 64, 31, 31, 8, 8] fp32.
// KH=KW=8, SH=SW=4, no padding.
//
// Round 10 = round 6/7 structure (8192 one-shot blocks -- rounds 8/9 proved
// persistent blocks regress) + PACKED FP32 FMA (v_pk_fma_f32 via f32x2 +
// __builtin_elementwise_fma). Round 6/7 counters: VALUBusy 43% ~= 26us of
// issue vs ~9us useful FMA -> compute phase is VALU-issue-bound. Packing
// adjacent ox pairs (same ra[j] broadcast, rb consecutive pair) cuts the
// inner 48 FMA/row to 22 pk + 4 scalar = 26 issue slots (-46%), and
// rebalances the wave tasks (heaviest 364 -> ~186).
//
// Structure (unchanged from round 6/7):
//  - block = 320 threads = 5 waves; wave k computes output row oy=k for 62
//    windows; rows 5..7 via corr(dy,dx)=corr(-dy,-dx) (reverse + 1 edge).
//  - results assembled in LDS (15.9 KB), streamed out as contiguous
//    full-line float4 runs (round 5: scattered 32B stores = 3.75x write amp).
//  - LDS float4 slot XOR-swizzled by (w&7): conflict-free write + read.

#define NH 31
#define NW 31

typedef float f32x4 __attribute__((ext_vector_type(4)));
typedef float f32x2 __attribute__((ext_vector_type(2)));

__device__ __forceinline__ void loadrow(const float* p, float r[8]) {
  f32x4 a = *reinterpret_cast<const f32x4*>(p);
  f32x4 b = *reinterpret_cast<const f32x4*>(p + 4);
  r[0] = a.x; r[1] = a.y; r[2] = a.z; r[3] = a.w;
  r[4] = b.x; r[5] = b.y; r[6] = b.z; r[7] = b.w;
}

// Task for dy = -D (output row oy = 4-D), D in 1..4. Packed over ox pairs:
// acc2[p] = {acc[2p], acc[2p+1]}, acc[ox] = sum_{i>=D, j} W[i][j]*W[i-D][j+ox-4].
// e (if WE) = sum_{i>=D} sum_{j=4..7} W[i-D][j]*W[i][j-4]  (mirror edge).
template <int D, bool WE>
__device__ __forceinline__ void corr_task_pk(const float* src, f32x2 acc2[4], float& e) {
  float R[D + 1][8];
  f32x2 e2 = {0.f, 0.f};
#pragma unroll
  for (int i = 0; i < 8; ++i) {
    const int ca = i % (D + 1);
    loadrow(src + i * 128, R[ca]);
    if (i >= D) {
      const int cb = (i - D) % (D + 1);
      const float(&ra)[8] = R[ca];
      const float(&rb)[8] = R[cb];
      // pair p covers ox = 2p,2p+1 (dx = 2p-4, 2p-3); packed j-range where
      // BOTH lanes in-window: j in [max(0,4-2p), min(7,10-2p)].
#pragma unroll
      for (int p = 0; p < 4; ++p) {
        const int j0 = (4 - 2 * p) > 0 ? (4 - 2 * p) : 0;
        const int j1 = (10 - 2 * p) < 7 ? (10 - 2 * p) : 7;
#pragma unroll
        for (int j = j0; j <= j1; ++j) {
          f32x2 a = {ra[j], ra[j]};
          f32x2 b = {rb[j + 2 * p - 4], rb[j + 2 * p - 3]};
          acc2[p] = __builtin_elementwise_fma(a, b, acc2[p]);
        }
      }
      // scalar leftovers (one lane of the pair out-of-window):
      acc2[0].y = fmaf(ra[3], rb[0], acc2[0].y);  // ox=1, j=3
      acc2[1].y = fmaf(ra[1], rb[0], acc2[1].y);  // ox=3, j=1
      acc2[2].x = fmaf(ra[7], rb[7], acc2[2].x);  // ox=4, j=7
      acc2[3].x = fmaf(ra[5], rb[7], acc2[3].x);  // ox=6, j=5
      if (WE) {
        f32x2 b0 = {rb[4], rb[5]}, a0 = {ra[0], ra[1]};
        f32x2 b1 = {rb[6], rb[7]}, a1 = {ra[2], ra[3]};
        e2 = __builtin_elementwise_fma(b0, a0, e2);
        e2 = __builtin_elementwise_fma(b1, a1, e2);
      }
    }
  }
  if (WE) e = e2.x + e2.y;
}

// dy = 0 task: acc2[0]={acc[0],acc[1]}, acc2[1]={acc[2],acc[3]}, a4=acc[4].
__device__ __forceinline__ void corr_task0_pk(const float* src, f32x2 acc2[2], float& a4) {
  f32x2 s2 = {0.f, 0.f};
#pragma unroll
  for (int i = 0; i < 8; ++i) {
    float r[8];
    loadrow(src + i * 128, r);
#pragma unroll
    for (int j = 4; j <= 7; ++j) {  // ox 0,1 packed
      f32x2 a = {r[j], r[j]};
      f32x2 b = {r[j - 4], r[j - 3]};
      acc2[0] = __builtin_elementwise_fma(a, b, acc2[0]);
    }
    acc2[0].y = fmaf(r[3], r[0], acc2[0].y);  // ox=1, j=3
#pragma unroll
    for (int j = 2; j <= 7; ++j) {  // ox 2,3 packed
      f32x2 a = {r[j], r[j]};
      f32x2 b = {r[j - 2], r[j - 1]};
      acc2[1] = __builtin_elementwise_fma(a, b, acc2[1]);
    }
    acc2[1].y = fmaf(r[1], r[0], acc2[1].y);  // ox=3, j=1
#pragma unroll
    for (int j = 0; j < 8; j += 2) {          // ox=4: sum of squares, packed
      f32x2 v = {r[j], r[j + 1]};
      s2 = __builtin_elementwise_fma(v, v, s2);
    }
  }
  a4 = s2.x + s2.y;
}

__global__ __launch_bounds__(320) void lacorr2d_kernel(
    const float* __restrict__ x, float* __restrict__ out) {
  __shared__ __align__(16) float lds[2][31][64];

  const int wave = threadIdx.x >> 6;   // 0..4 : oy task
  const int lane = threadIdx.x & 63;
  const int w    = lane & 31;          // window col (31 = dead lane)
  const int hh   = lane >> 5;          // 0/1 within window-row pair
  const int hp   = blockIdx.x & 15;    // window-row pair
  const int bc   = blockIdx.x >> 4;    // 0..511
  const int h    = hp * 2 + hh;        // 0..31 (31 invalid)
  const bool valid = (w < NW) && (h < NH);
  const int hc = valid ? h : 0;
  const int wc = valid ? w : 0;

  const float* src = x + (size_t)bc * (128 * 128) + (size_t)(hc * 4) * 128 + wc * 4;
  float* wbase = &lds[hh][wc][0];
  const int sw = wc & 7;  // swizzle key

  f32x2 acc2[4] = {{0.f, 0.f}, {0.f, 0.f}, {0.f, 0.f}, {0.f, 0.f}};
  float e = 0.f;

#define LDS_ST(e4, a, b, c, d)                                              \
  do {                                                                      \
    f32x4 v_ = {a, b, c, d};                                                \
    *reinterpret_cast<f32x4*>(wbase + (((e4) ^ sw) << 2)) = v_;             \
  } while (0)

  if (wave == 0) {                     // oy=0, dy=-4 (unpaired row)
    corr_task_pk<4, false>(src, acc2, e);
    if (valid) {
      LDS_ST(0, acc2[0].x, acc2[0].y, acc2[1].x, acc2[1].y);
      LDS_ST(1, acc2[2].x, acc2[2].y, acc2[3].x, acc2[3].y);
    }
  } else if (wave == 1) {              // oy=1 & mirror oy=7
    corr_task_pk<3, true>(src, acc2, e);
    if (valid) {
      LDS_ST(2,  acc2[0].x, acc2[0].y, acc2[1].x, acc2[1].y);
      LDS_ST(3,  acc2[2].x, acc2[2].y, acc2[3].x, acc2[3].y);
      LDS_ST(14, e,         acc2[3].y, acc2[3].x, acc2[2].y);
      LDS_ST(15, acc2[2].x, acc2[1].y, acc2[1].x, acc2[0].y);
    }
  } else if (wave == 2) {              // oy=2 & mirror oy=6
    corr_task_pk<2, true>(src, acc2, e);
    if (valid) {
      LDS_ST(4,  acc2[0].x, acc2[0].y, acc2[1].x, acc2[1].y);
      LDS_ST(5,  acc2[2].x, acc2[2].y, acc2[3].x, acc2[3].y);
      LDS_ST(12, e,         acc2[3].y, acc2[3].x, acc2[2].y);
      LDS_ST(13, acc2[2].x, acc2[1].y, acc2[1].x, acc2[0].y);
    }
  } else if (wave == 3) {              // oy=3 & mirror oy=5
    corr_task_pk<1, true>(src, acc2, e);
    if (valid) {
      LDS_ST(6,  acc2[0].x, acc2[0].y, acc2[1].x, acc2[1].y);
      LDS_ST(7,  acc2[2].x, acc2[2].y, acc2[3].x, acc2[3].y);
      LDS_ST(10, e,         acc2[3].y, acc2[3].x, acc2[2].y);
      LDS_ST(11, acc2[2].x, acc2[1].y, acc2[1].x, acc2[0].y);
    }
  } else {                             // oy=4, dy=0 (self-mirrored row)
    float a4 = 0.f;
    corr_task0_pk(src, acc2, a4);
    if (valid) {
      LDS_ST(8, acc2[0].x, acc2[0].y, acc2[1].x, acc2[1].y);
      LDS_ST(9, a4,        acc2[1].y, acc2[1].x, acc2[0].y);
    }
  }
#undef LDS_ST

  __syncthreads();

  // Stream the assembled tile to global: two contiguous 7936 B runs
  // (31 windows x 256 B each), full cache lines, lane-consecutive float4s.
#pragma unroll
  for (int h2 = 0; h2 < 2; ++h2) {
    const int hrow = hp * 2 + h2;
    if (hrow >= NH) continue;  // block-uniform
    float* orun = out + (size_t)(bc * NH + hrow) * NW * 64;
    for (int idx = threadIdx.x; idx < NW * 16; idx += 320) {
      const int ww = idx >> 4;
      const int e4 = idx & 15;
      f32x4 v = *reinterpret_cast<const f32x4*>(&lds[h2][ww][(e4 ^ (ww & 7)) << 2]);
      *reinterpret_cast<f32x4*>(orun + idx * 4) = v;
    }
  }
}

extern "C" void kernel_launch(void* const* d_in, const int* in_sizes, int n_in,
                              void* d_out, int out_size, void* d_ws, size_t ws_size,
                              hipStream_t stream) {
  const float* x = (const float*)d_in[0];
  float* out = (float*)d_out;
  // 512 bc-planes x 16 window-row pairs
  lacorr2d_kernel<<<512 * 16, 320, 0, stream>>>(x, out);
}

// Round 11
// 41.965 us; speedup vs baseline: 1.8406x; 1.0012x over previous
//
#include <hip/hip_runtime.h>

// Local windowed 2D autocorrelation.
// x: [8, 64, 128, 128] fp32; out: [8, 64, 31, 31, 8, 8] fp32.
// KH=KW=8, SH=SW=4, no padding.
//
// Round 11 = round 10 + PREFETCH-ALL-ROWS. Round 10's rolling row buffer
// serialized load->use each i-iteration (~250cyc latency x 5-8 iters per
// task with only ~2 waves/SIMD to hide it). Now all 16 row loads issue
// back-to-back (independent -> one L1 latency total), then the packed-FMA
// burst runs unstalled. Live set ~90 VGPR (64 window + 8 acc + addr) fits:
// __launch_bounds__(320,2) caps at 256 (round 2 lesson: never force below
// the live set; round 1 lesson: only ONE oy-task's accs live per wave).
//
// Structure (unchanged from round 10):
//  - 8192 one-shot blocks (rounds 8/9: persistent blocks regress).
//  - block = 320 threads = 5 waves; wave k computes output row oy=k for 62
//    windows; rows 5..7 via corr(dy,dx)=corr(-dy,-dx) (reverse + 1 edge).
//  - packed fp32 FMA (v_pk_fma_f32 via f32x2): 48 -> 26 issue slots/row.
//  - results assembled in LDS (15.9 KB), streamed out as contiguous
//    full-line float4 runs (round 5: scattered 32B stores = 3.75x amp).
//  - LDS float4 slot XOR-swizzled by (w&7): conflict-free write + read.

#define NH 31
#define NW 31

typedef float f32x4 __attribute__((ext_vector_type(4)));
typedef float f32x2 __attribute__((ext_vector_type(2)));

__device__ __forceinline__ void loadrow(const float* p, float r[8]) {
  f32x4 a = *reinterpret_cast<const f32x4*>(p);
  f32x4 b = *reinterpret_cast<const f32x4*>(p + 4);
  r[0] = a.x; r[1] = a.y; r[2] = a.z; r[3] = a.w;
  r[4] = b.x; r[5] = b.y; r[6] = b.z; r[7] = b.w;
}

// Task for dy = -D (output row oy = 4-D), D in 1..4. Packed over ox pairs:
// acc2[p] = {acc[2p], acc[2p+1]}, acc[ox] = sum_{i>=D, j} W[i][j]*W[i-D][j+ox-4].
// e (if WE) = sum_{i>=D} sum_{j=4..7} W[i-D][j]*W[i][j-4]  (mirror edge).
template <int D, bool WE>
__device__ __forceinline__ void corr_task_pk(const float* src, f32x2 acc2[4], float& e) {
  float R[8][8];
#pragma unroll
  for (int i = 0; i < 8; ++i) loadrow(src + i * 128, R[i]);  // all independent

  f32x2 e2 = {0.f, 0.f};
#pragma unroll
  for (int i = D; i < 8; ++i) {
    const float(&ra)[8] = R[i];
    const float(&rb)[8] = R[i - D];
    // pair p covers ox = 2p,2p+1 (dx = 2p-4, 2p-3); packed j-range where
    // BOTH lanes in-window: j in [max(0,4-2p), min(7,10-2p)].
#pragma unroll
    for (int p = 0; p < 4; ++p) {
      const int j0 = (4 - 2 * p) > 0 ? (4 - 2 * p) : 0;
      const int j1 = (10 - 2 * p) < 7 ? (10 - 2 * p) : 7;
#pragma unroll
      for (int j = j0; j <= j1; ++j) {
        f32x2 a = {ra[j], ra[j]};
        f32x2 b = {rb[j + 2 * p - 4], rb[j + 2 * p - 3]};
        acc2[p] = __builtin_elementwise_fma(a, b, acc2[p]);
      }
    }
    // scalar leftovers (one lane of the pair out-of-window):
    acc2[0].y = fmaf(ra[3], rb[0], acc2[0].y);  // ox=1, j=3
    acc2[1].y = fmaf(ra[1], rb[0], acc2[1].y);  // ox=3, j=1
    acc2[2].x = fmaf(ra[7], rb[7], acc2[2].x);  // ox=4, j=7
    acc2[3].x = fmaf(ra[5], rb[7], acc2[3].x);  // ox=6, j=5
    if (WE) {
      f32x2 b0 = {rb[4], rb[5]}, a0 = {ra[0], ra[1]};
      f32x2 b1 = {rb[6], rb[7]}, a1 = {ra[2], ra[3]};
      e2 = __builtin_elementwise_fma(b0, a0, e2);
      e2 = __builtin_elementwise_fma(b1, a1, e2);
    }
  }
  if (WE) e = e2.x + e2.y;
}

// dy = 0 task: acc2[0]={acc[0],acc[1]}, acc2[1]={acc[2],acc[3]}, a4=acc[4].
__device__ __forceinline__ void corr_task0_pk(const float* src, f32x2 acc2[2], float& a4) {
  float R[8][8];
#pragma unroll
  for (int i = 0; i < 8; ++i) loadrow(src + i * 128, R[i]);

  f32x2 s2 = {0.f, 0.f};
#pragma unroll
  for (int i = 0; i < 8; ++i) {
    const float(&r)[8] = R[i];
#pragma unroll
    for (int j = 4; j <= 7; ++j) {  // ox 0,1 packed
      f32x2 a = {r[j], r[j]};
      f32x2 b = {r[j - 4], r[j - 3]};
      acc2[0] = __builtin_elementwise_fma(a, b, acc2[0]);
    }
    acc2[0].y = fmaf(r[3], r[0], acc2[0].y);  // ox=1, j=3
#pragma unroll
    for (int j = 2; j <= 7; ++j) {  // ox 2,3 packed
      f32x2 a = {r[j], r[j]};
      f32x2 b = {r[j - 2], r[j - 1]};
      acc2[1] = __builtin_elementwise_fma(a, b, acc2[1]);
    }
    acc2[1].y = fmaf(r[1], r[0], acc2[1].y);  // ox=3, j=1
#pragma unroll
    for (int j = 0; j < 8; j += 2) {          // ox=4: sum of squares, packed
      f32x2 v = {r[j], r[j + 1]};
      s2 = __builtin_elementwise_fma(v, v, s2);
    }
  }
  a4 = s2.x + s2.y;
}

__global__ __launch_bounds__(320, 2) void lacorr2d_kernel(
    const float* __restrict__ x, float* __restrict__ out) {
  __shared__ __align__(16) float lds[2][31][64];

  const int wave = threadIdx.x >> 6;   // 0..4 : oy task
  const int lane = threadIdx.x & 63;
  const int w    = lane & 31;          // window col (31 = dead lane)
  const int hh   = lane >> 5;          // 0/1 within window-row pair
  const int hp   = blockIdx.x & 15;    // window-row pair
  const int bc   = blockIdx.x >> 4;    // 0..511
  const int h    = hp * 2 + hh;        // 0..31 (31 invalid)
  const bool valid = (w < NW) && (h < NH);
  const int hc = valid ? h : 0;
  const int wc = valid ? w : 0;

  const float* src = x + (size_t)bc * (128 * 128) + (size_t)(hc * 4) * 128 + wc * 4;
  float* wbase = &lds[hh][wc][0];
  const int sw = wc & 7;  // swizzle key

  f32x2 acc2[4] = {{0.f, 0.f}, {0.f, 0.f}, {0.f, 0.f}, {0.f, 0.f}};
  float e = 0.f;

#define LDS_ST(e4, a, b, c, d)                                              \
  do {                                                                      \
    f32x4 v_ = {a, b, c, d};                                                \
    *reinterpret_cast<f32x4*>(wbase + (((e4) ^ sw) << 2)) = v_;             \
  } while (0)

  if (wave == 0) {                     // oy=0, dy=-4 (unpaired row)
    corr_task_pk<4, false>(src, acc2, e);
    if (valid) {
      LDS_ST(0, acc2[0].x, acc2[0].y, acc2[1].x, acc2[1].y);
      LDS_ST(1, acc2[2].x, acc2[2].y, acc2[3].x, acc2[3].y);
    }
  } else if (wave == 1) {              // oy=1 & mirror oy=7
    corr_task_pk<3, true>(src, acc2, e);
    if (valid) {
      LDS_ST(2,  acc2[0].x, acc2[0].y, acc2[1].x, acc2[1].y);
      LDS_ST(3,  acc2[2].x, acc2[2].y, acc2[3].x, acc2[3].y);
      LDS_ST(14, e,         acc2[3].y, acc2[3].x, acc2[2].y);
      LDS_ST(15, acc2[2].x, acc2[1].y, acc2[1].x, acc2[0].y);
    }
  } else if (wave == 2) {              // oy=2 & mirror oy=6
    corr_task_pk<2, true>(src, acc2, e);
    if (valid) {
      LDS_ST(4,  acc2[0].x, acc2[0].y, acc2[1].x, acc2[1].y);
      LDS_ST(5,  acc2[2].x, acc2[2].y, acc2[3].x, acc2[3].y);
      LDS_ST(12, e,         acc2[3].y, acc2[3].x, acc2[2].y);
      LDS_ST(13, acc2[2].x, acc2[1].y, acc2[1].x, acc2[0].y);
    }
  } else if (wave == 3) {              // oy=3 & mirror oy=5
    corr_task_pk<1, true>(src, acc2, e);
    if (valid) {
      LDS_ST(6,  acc2[0].x, acc2[0].y, acc2[1].x, acc2[1].y);
      LDS_ST(7,  acc2[2].x, acc2[2].y, acc2[3].x, acc2[3].y);
      LDS_ST(10, e,         acc2[3].y, acc2[3].x, acc2[2].y);
      LDS_ST(11, acc2[2].x, acc2[1].y, acc2[1].x, acc2[0].y);
    }
  } else {                             // oy=4, dy=0 (self-mirrored row)
    float a4 = 0.f;
    corr_task0_pk(src, acc2, a4);
    if (valid) {
      LDS_ST(8, acc2[0].x, acc2[0].y, acc2[1].x, acc2[1].y);
      LDS_ST(9, a4,        acc2[1].y, acc2[1].x, acc2[0].y);
    }
  }
#undef LDS_ST

  __syncthreads();

  // Stream the assembled tile to global: two contiguous 7936 B runs
  // (31 windows x 256 B each), full cache lines, lane-consecutive float4s.
#pragma unroll
  for (int h2 = 0; h2 < 2; ++h2) {
    const int hrow = hp * 2 + h2;
    if (hrow >= NH) continue;  // block-uniform
    float* orun = out + (size_t)(bc * NH + hrow) * NW * 64;
    for (int idx = threadIdx.x; idx < NW * 16; idx += 320) {
      const int ww = idx >> 4;
      const int e4 = idx & 15;
      f32x4 v = *reinterpret_cast<const f32x4*>(&lds[h2][ww][(e4 ^ (ww & 7)) << 2]);
      *reinterpret_cast<f32x4*>(orun + idx * 4) = v;
    }
  }
}

extern "C" void kernel_launch(void* const* d_in, const int* in_sizes, int n_in,
                              void* d_out, int out_size, void* d_ws, size_t ws_size,
                              hipStream_t stream) {
  const float* x = (const float*)d_in[0];
  float* out = (float*)d_out;
  // 512 bc-planes x 16 window-row pairs
  lacorr2d_kernel<<<512 * 16, 320, 0, stream>>>(x, out);
}